// Round 6
// baseline (794.589 us; speedup 1.0000x reference)
//
#include <hip/hip_runtime.h>
#include <cstdint>
#include <cstddef>

// Problem constants
#define B_ 8
#define S_ 4096
#define H_ 1024
#define NH_ 16
#define DH_ 64
#define MTOK 32768  // B_*S_

typedef unsigned short u16;
typedef __bf16 bf16x8 __attribute__((ext_vector_type(8)));
typedef u16 u16x8 __attribute__((ext_vector_type(8)));
typedef u16 u16x4 __attribute__((ext_vector_type(4)));
typedef float f32x4 __attribute__((ext_vector_type(4)));

#define DEVFN static __device__ __forceinline__

DEVFN float bf2f(u16 u) {
  union { uint32_t u; float f; } c; c.u = ((uint32_t)u) << 16; return c.f;
}
DEVFN u16 f2bf(float f) {
  union { float f; uint32_t u; } c; c.f = f;
  uint32_t r = c.u + 0x7fffu + ((c.u >> 16) & 1u);  // RNE
  return (u16)(r >> 16);
}
DEVFN void gload16(const void* g, void* lds_p) {
  __builtin_amdgcn_global_load_lds(
      (const __attribute__((address_space(1))) void*)g,
      (__attribute__((address_space(3))) void*)lds_p, 16, 0, 0);
}

// ---------------------------------------------------------------------------
// Convert fp32 X -> bf16 Xb
__global__ __launch_bounds__(256) void k_cvt_x(const float* __restrict__ x,
                                               u16* __restrict__ xb) {
  const size_t i = ((size_t)blockIdx.x * 256 + threadIdx.x) * 8;
  f32x4 a = *(const f32x4*)(x + i);
  f32x4 b = *(const f32x4*)(x + i + 4);
  u16x8 o;
#pragma unroll
  for (int j = 0; j < 4; ++j) { o[j] = f2bf(a[j]); o[4 + j] = f2bf(b[j]); }
  *(u16x8*)(xb + i) = o;
}

// ---------------------------------------------------------------------------
// Wt[g*1024+n][k] = W_g[k][n]  (bf16, B^T layout for the GEMM)
__global__ __launch_bounds__(256) void k_wt(const float* __restrict__ Wq,
                                            const float* __restrict__ Wk,
                                            const float* __restrict__ Wv,
                                            u16* __restrict__ Wt) {
  const int n = blockIdx.x * 256 + threadIdx.x;  // 0..1023
  const int kc = blockIdx.y;                     // k-chunk of 8
  const int g = blockIdx.z;                      // 0..2
  const float* W = (g == 0) ? Wq : (g == 1) ? Wk : Wv;
  u16x8 o;
#pragma unroll
  for (int j = 0; j < 8; ++j) o[j] = f2bf(W[(size_t)(kc * 8 + j) * 1024 + n]);
  *(u16x8*)(Wt + ((size_t)(g * 1024 + n)) * 1024 + kc * 8) = o;
}

// ---------------------------------------------------------------------------
// Unified GEMM: 128x128 tile, BK=64, 4 waves (2Mx2N), SINGLE-buffered 32KB
// LDS -> 5 blocks/CU TLP. st_16x32 swizzle (linear LDS dest via gload_lds,
// pre-swizzled global source, XOR on ds_read). Per K-tile: stage -> sync ->
// ds_read+MFMA (compiler-interleaved lgkmcnt) -> sync. Epilogue: C staged in
// the same 32KB LDS -> coalesced u16x8 stores.
// EPI=0 (QKV): bias + elu + fused per-(row,head) L2 norm for Q/K. grid 6144.
// EPI=1 (ctx): plain store, Bt per-batch (Bt + batch*1M). grid 2048.
template <int EPI>
__global__ __launch_bounds__(256, 4) void k_g(
    const u16* __restrict__ A, const u16* __restrict__ Bt,
    u16* __restrict__ o0, u16* __restrict__ o1, u16* __restrict__ o2,
    const float* __restrict__ bias0, const float* __restrict__ bias1,
    const float* __restrict__ bias2) {
  __shared__ __align__(16) char lds[32768];
  const int tid = threadIdx.x;
  const int w = tid >> 6, l = tid & 63;
  const int wm = w >> 1, wn = w & 1;

  // XCD-chunked block remap for L2 A-panel sharing.
  const int bid = (int)blockIdx.x;
  int bx, by;
  if (EPI == 0) {  // 6144 blocks: 256 bx x 24 by
    const int virt = (bid & 7) * 768 + (bid >> 3);
    const int bxi = virt & 7;
    const int tmp = virt >> 3;  // 0..767
    by = tmp % 24;
    bx = (tmp / 24) * 8 + bxi;
  } else {         // 2048 blocks: 256 bx x 8 by
    const int virt = (bid & 7) * 256 + (bid >> 3);
    const int inner = virt & 31;
    by = inner & 7;
    bx = (virt >> 5) * 4 + (inner >> 3);
  }
  const long row0 = (long)bx * 128;
  const long col0 = (long)by * 128;
  const u16* Bt2 = Bt + (EPI == 1 ? ((size_t)(row0 >> 12) << 20) : (size_t)0);
  const int seg = (EPI == 0) ? (by >> 3) : 0;  // 0:Q 1:K 2:V
  const int colN = (EPI == 0) ? ((by & 7) * 128) : (int)col0;

  // staging source (pre-swizzled k-offset)
  const int koff = ((tid & 3) * 16) ^ ((tid & 32) ? 32 : 0);  // bytes
  const u16* srcA = A + (row0 + (tid >> 2)) * 1024 + (koff >> 1);
  const u16* srcB = Bt2 + (col0 + (tid >> 2)) * 1024 + (koff >> 1);
  char* dA = lds + w * 1024;
  char* dB = lds + 16384 + w * 1024;

  // LDS read bases (swizzled); layout {A:0,B:16384} + kh*8192 + row*64B
  const int rkoff = ((l >> 4) * 16) ^ ((l & 8) ? 32 : 0);
  const char* pA = lds + (wm * 64 + (l & 15)) * 64 + rkoff;
  const char* pB = lds + 16384 + (wn * 64 + (l & 15)) * 64 + rkoff;

  f32x4 acc[4][4];
#pragma unroll
  for (int i = 0; i < 4; ++i)
#pragma unroll
    for (int j = 0; j < 4; ++j) acc[i][j] = (f32x4){0.f, 0.f, 0.f, 0.f};

  for (int t = 0; t < 16; ++t) {
    const u16* sA = srcA + (size_t)t * 64;
    const u16* sB = srcB + (size_t)t * 64;
#pragma unroll
    for (int kh = 0; kh < 2; ++kh)
#pragma unroll
      for (int i = 0; i < 2; ++i) {
        gload16(sA + kh * 32 + (size_t)i * 65536, dA + kh * 8192 + i * 4096);
        gload16(sB + kh * 32 + (size_t)i * 65536, dB + kh * 8192 + i * 4096);
      }
    __syncthreads();  // drains vmcnt -> tile visible to all waves
    bf16x8 af[4][2], bfg[4][2];
#pragma unroll
    for (int kh = 0; kh < 2; ++kh)
#pragma unroll
      for (int mf = 0; mf < 4; ++mf)
        af[mf][kh] = *(const bf16x8*)(pA + mf * 1024 + kh * 8192);
#pragma unroll
    for (int kh = 0; kh < 2; ++kh)
#pragma unroll
      for (int nf = 0; nf < 4; ++nf)
        bfg[nf][kh] = *(const bf16x8*)(pB + nf * 1024 + kh * 8192);
    __builtin_amdgcn_s_setprio(1);
#pragma unroll
    for (int mf = 0; mf < 4; ++mf)
#pragma unroll
      for (int nf = 0; nf < 4; ++nf)
#pragma unroll
        for (int kh = 0; kh < 2; ++kh)
          acc[mf][nf] = __builtin_amdgcn_mfma_f32_16x16x32_bf16(
              af[mf][kh], bfg[nf][kh], acc[mf][nf], 0, 0, 0);
    __builtin_amdgcn_s_setprio(0);
    __syncthreads();  // all reads done before next stage overwrites
  }

  // ---- Epilogue: C (bf16) -> LDS (32KB, col-group XOR swizzle), coalesced out
  u16* cl = (u16*)lds;
  const float* bias =
      (EPI == 0) ? ((seg == 0) ? bias0 : (seg == 1) ? bias1 : bias2) : nullptr;
  const int rb = wm * 64 + ((l >> 4) << 2);
  const int cbl = wn * 64 + (l & 15);
#pragma unroll
  for (int nf = 0; nf < 4; ++nf) {
    const int col = cbl + nf * 16;
    const float bv_ = (EPI == 0) ? bias[colN + col] : 0.f;
#pragma unroll
    for (int mf = 0; mf < 4; ++mf)
#pragma unroll
      for (int r = 0; r < 4; ++r) {
        const int row = rb + mf * 16 + r;
        float v = acc[mf][nf][r];
        if (EPI == 0) {
          v += bv_;
          if (seg < 2) v = v > 0.f ? v : expm1f(v);  // elu
        }
        cl[row * 128 + (((col >> 4) ^ (row & 7)) << 4) + (col & 15)] = f2bf(v);
      }
  }
  __syncthreads();
  u16* outp = (EPI == 0) ? ((seg == 0) ? o0 : (seg == 1) ? o1 : o2) : o0;
  const int cg = (tid & 15) >> 1;   // 32B col-group
  const int lo = (tid & 1) << 4;    // byte within group
#pragma unroll
  for (int i = 0; i < 8; ++i) {
    const int row = i * 16 + (tid >> 4);
    u16x8 val = *(const u16x8*)((const char*)cl + row * 256 +
                                ((cg ^ (row & 7)) << 5) + lo);
    if (EPI == 0 && seg < 2) {  // fused per-(row,head) L2 norm (8 lanes/head)
      float f[8], ss = 0.f;
#pragma unroll
      for (int j = 0; j < 8; ++j) { f[j] = bf2f(val[j]); ss += f[j] * f[j]; }
      ss += __shfl_xor(ss, 1);
      ss += __shfl_xor(ss, 2);
      ss += __shfl_xor(ss, 4);
      const float rn = rsqrtf(ss);
#pragma unroll
      for (int j = 0; j < 8; ++j) val[j] = f2bf(f[j] * rn);
    }
    *(u16x8*)(outp + (size_t)(row0 + row) * 1024 + colN + (tid & 15) * 8) = val;
  }
}

// ---------------------------------------------------------------------------
// kv partials via MFMA: kvp[sc][b][h][d][e] = sum_{s in quarter} kn[s,d]*v[s,e]
// Block = (b,h,sc-quarter of 1024 tokens); 4 waves, each owns 256 tokens and a
// private LDS region: stage 64x64 knT/vT tiles (transposed reg-stage, b32-pair
// writes, XOR-swizzled rows), 2x16 MFMA per tile, no barriers in the loop.
// End: LDS reduction of the 4 per-wave partials (padded rows), write kvp.
__global__ __launch_bounds__(256) void k_kv(const u16* __restrict__ kn,
                                            const u16* __restrict__ vv,
                                            float* __restrict__ kvp) {
  __shared__ __align__(16) char lds[69632];  // 4 regions x 17408 B
  const int tid = threadIdx.x, w = tid >> 6, l = tid & 63;
  const int bid = blockIdx.x;  // sc + 4*(h + 16*b)
  const int sc = bid & 3, h = (bid >> 2) & 15, b = bid >> 6;
  const int tp = l >> 3, dgrp = l & 7;
  char* myk = lds + w * 17408;       // knT tile [64 d][64 s] u16 (128B rows)
  char* myv = myk + 8192;            // vT tile
  const long Tw = (long)b * 4096 + sc * 1024 + w * 256;
  const int d0 = dgrp * 8;

  f32x4 acc[4][4];
#pragma unroll
  for (int i = 0; i < 4; ++i)
#pragma unroll
    for (int j = 0; j < 4; ++j) acc[i][j] = (f32x4){0.f, 0.f, 0.f, 0.f};

  for (int st = 0; st < 4; ++st) {
    // ---- transpose-stage 64 tokens x 64 d for kn and v
#pragma unroll
    for (int ro = 0; ro < 4; ++ro) {
      const int tl = ro * 16 + tp * 2;  // even local token
      const long T = Tw + st * 64 + tl;
      const u16* kp = kn + (size_t)T * 1024 + h * 64 + d0;
      const u16* vp = vv + (size_t)T * 1024 + h * 64 + d0;
      u16x8 k0 = *(const u16x8*)kp, k1 = *(const u16x8*)(kp + 1024);
      u16x8 v0 = *(const u16x8*)vp, v1 = *(const u16x8*)(vp + 1024);
#pragma unroll
      for (int j = 0; j < 8; ++j) {
        const int d = d0 + j;
        const int sw = (d & 8) ? 32 : 0;
        *(uint32_t*)(myk + d * 128 + ((tl * 2) ^ sw)) =
            (uint32_t)k0[j] | ((uint32_t)k1[j] << 16);
        *(uint32_t*)(myv + d * 128 + ((tl * 2) ^ sw)) =
            (uint32_t)v0[j] | ((uint32_t)v1[j] << 16);
      }
    }
    // ---- compute: D[d][e] += knT-tile . vT-tile  (K = 64 = 2 slices)
#pragma unroll
    for (int ksl = 0; ksl < 2; ++ksl) {
      const int sb = (ksl * 64 + (l >> 4) * 16) ^ ((l & 8) ? 32 : 0);
      bf16x8 a[4], bb[4];
#pragma unroll
      for (int mf = 0; mf < 4; ++mf)
        a[mf] = *(const bf16x8*)(myk + (mf * 16 + (l & 15)) * 128 + sb);
#pragma unroll
      for (int nf = 0; nf < 4; ++nf)
        bb[nf] = *(const bf16x8*)(myv + (nf * 16 + (l & 15)) * 128 + sb);
#pragma unroll
      for (int mf = 0; mf < 4; ++mf)
#pragma unroll
        for (int nf = 0; nf < 4; ++nf)
          acc[mf][nf] = __builtin_amdgcn_mfma_f32_16x16x32_bf16(
              a[mf], bb[nf], acc[mf][nf], 0, 0, 0);
    }
  }

  // ---- block reduction of 4 wave partials (rows padded to 68 f32)
  __syncthreads();
  float* lf = (float*)(lds + w * 17408);
#pragma unroll
  for (int mf = 0; mf < 4; ++mf)
#pragma unroll
    for (int nf = 0; nf < 4; ++nf)
#pragma unroll
      for (int r = 0; r < 4; ++r)
        lf[(mf * 16 + (l >> 4) * 4 + r) * 68 + nf * 16 + (l & 15)] =
            acc[mf][nf][r];
  __syncthreads();
  float* op = kvp + ((size_t)(sc * 8 + b) * 16 + h) * 4096;
  const float* l0 = (const float*)lds;
  const int dd = tid >> 2, eb = (tid & 3) * 16;
#pragma unroll
  for (int c = 0; c < 4; ++c) {
    f32x4 s = *(const f32x4*)(l0 + dd * 68 + eb + c * 4);
#pragma unroll
    for (int w2 = 1; w2 < 4; ++w2)
      s += *(const f32x4*)(l0 + w2 * 4352 + dd * 68 + eb + c * 4);
    *(f32x4*)(op + tid * 16 + c * 4) = s;
  }
}

// ---------------------------------------------------------------------------
// M2t[b][n][h*64+d] = (1/8) * sum_e kv[b,h][d][e] * Wd[h*64+e][n]   (bf16)
__global__ __launch_bounds__(256) void k_m2(const float* __restrict__ kvp,
                                            const float* __restrict__ Wd,
                                            u16* __restrict__ M2t) {
  const int tid = threadIdx.x;
  const int nb = blockIdx.x, h = blockIdx.y, b = blockIdx.z;
  const int d = tid >> 2, eg = tid & 3;
  const size_t kbase = (((size_t)(b * 16 + h)) * 64 + d) * 64 + eg * 16;
  float kvr[16];
#pragma unroll
  for (int c = 0; c < 4; ++c) {
    f32x4 s = *(const f32x4*)(kvp + kbase + c * 4);
#pragma unroll
    for (int sc = 1; sc < 4; ++sc)
      s += *(const f32x4*)(kvp + (size_t)sc * 524288 + kbase + c * 4);
#pragma unroll
    for (int j = 0; j < 4; ++j) kvr[c * 4 + j] = s[j];
  }
  const float* wcol = Wd + ((size_t)h * 64 + eg * 16) * 1024;
  for (int n = nb * 256; n < nb * 256 + 256; ++n) {
    float p = 0.f;
#pragma unroll
    for (int i = 0; i < 16; ++i) p += kvr[i] * wcol[(size_t)i * 1024 + n];
    p += __shfl_xor(p, 1);
    p += __shfl_xor(p, 2);
    if (eg == 0)
      M2t[((size_t)b * 1024 + n) * 1024 + h * 64 + d] = f2bf(p * 0.125f);
  }
}

// ---------------------------------------------------------------------------
// LayerNorm(hid + bd + xb) * gamma + beta  -> fp32 out
__global__ __launch_bounds__(256) void k_ln(const u16* __restrict__ hid,
                                            const u16* __restrict__ xb,
                                            const float* __restrict__ bd,
                                            const float* __restrict__ g,
                                            const float* __restrict__ be,
                                            float* __restrict__ out) {
  const int tid = threadIdx.x, w = tid >> 6, l = tid & 63;
  const size_t base = (size_t)blockIdx.x * 1024 + tid * 4;
  u16x4 h4 = *(const u16x4*)(hid + base);
  u16x4 x4 = *(const u16x4*)(xb + base);
  f32x4 bd4 = *(const f32x4*)(bd + tid * 4);
  float v[4];
#pragma unroll
  for (int j = 0; j < 4; ++j) v[j] = bf2f(h4[j]) + bf2f(x4[j]) + bd4[j];
  float s = v[0] + v[1] + v[2] + v[3];
  float ss = v[0] * v[0] + v[1] * v[1] + v[2] * v[2] + v[3] * v[3];
#pragma unroll
  for (int o = 32; o > 0; o >>= 1) {
    s += __shfl_xor(s, o);
    ss += __shfl_xor(ss, o);
  }
  __shared__ float red[8];
  if (l == 0) { red[w] = s; red[w + 4] = ss; }
  __syncthreads();
  s = red[0] + red[1] + red[2] + red[3];
  ss = red[4] + red[5] + red[6] + red[7];
  const float mu = s * (1.0f / 1024.0f);
  const float var = ss * (1.0f / 1024.0f) - mu * mu;
  const float rstd = rsqrtf(var + 1e-12f);
  f32x4 g4 = *(const f32x4*)(g + tid * 4);
  f32x4 b4 = *(const f32x4*)(be + tid * 4);
  f32x4 o;
#pragma unroll
  for (int j = 0; j < 4; ++j) o[j] = (v[j] - mu) * rstd * g4[j] + b4[j];
  *(f32x4*)(out + base) = o;
}

// ---------------------------------------------------------------------------
extern "C" void kernel_launch(void* const* d_in, const int* in_sizes, int n_in,
                              void* d_out, int out_size, void* d_ws,
                              size_t ws_size, hipStream_t stream) {
  const float* X = (const float*)d_in[0];
  const float* Wq = (const float*)d_in[1];
  const float* bq = (const float*)d_in[2];
  const float* Wk = (const float*)d_in[3];
  const float* bk = (const float*)d_in[4];
  const float* Wv = (const float*)d_in[5];
  const float* bv = (const float*)d_in[6];
  const float* Wd = (const float*)d_in[7];
  const float* bd = (const float*)d_in[8];
  const float* gamma = (const float*)d_in[9];
  const float* beta = (const float*)d_in[10];
  float* out = (float*)d_out;

  char* ws = (char*)d_ws;
  u16* Xb = (u16*)(ws);                       // 64 MiB
  u16* Wt = (u16*)(ws + 67108864);            // 6 MiB  [3072][1024] bf16
  u16* eq = (u16*)(ws + 73400320);            // 64 MiB (qn, normalized in epi)
  u16* ek = (u16*)(ws + 140509184);           // 64 MiB (kn; reused as hid)
  u16* vb = (u16*)(ws + 207618048);           // 64 MiB
  float* kvp = (float*)(ws + 276824064);      // 8 MiB (4 partials)
  u16* M2t = (u16*)(ws + 285212672);          // 16 MiB  [8][1024][1024] bf16
  // total ws use: 301,989,888 bytes

  k_cvt_x<<<16384, 256, 0, stream>>>(X, Xb);
  k_wt<<<dim3(4, 128, 3), 256, 0, stream>>>(Wq, Wk, Wv, Wt);
  k_g<0><<<6144, 256, 0, stream>>>(Xb, Wt, eq, ek, vb, bq, bk, bv);
  k_kv<<<512, 256, 0, stream>>>(ek, vb, kvp);
  k_m2<<<dim3(4, 16, 8), 256, 0, stream>>>(kvp, Wd, M2t);
  k_g<1><<<2048, 256, 0, stream>>>(eq, M2t, ek, nullptr, nullptr, nullptr,
                                   nullptr, nullptr);
  k_ln<<<32768, 256, 0, stream>>>(ek, Xb, bd, gamma, beta, out);
}

// Round 7
// 770.493 us; speedup vs baseline: 1.0313x; 1.0313x over previous
//
#include <hip/hip_runtime.h>
#include <cstdint>
#include <cstddef>

// Problem constants
#define B_ 8
#define S_ 4096
#define H_ 1024
#define NH_ 16
#define DH_ 64
#define MTOK 32768  // B_*S_

typedef unsigned short u16;
typedef __bf16 bf16x8 __attribute__((ext_vector_type(8)));
typedef u16 u16x8 __attribute__((ext_vector_type(8)));
typedef u16 u16x4 __attribute__((ext_vector_type(4)));
typedef float f32x4 __attribute__((ext_vector_type(4)));

#define DEVFN static __device__ __forceinline__

DEVFN float bf2f(u16 u) {
  union { uint32_t u; float f; } c; c.u = ((uint32_t)u) << 16; return c.f;
}
DEVFN u16 f2bf(float f) {
  union { float f; uint32_t u; } c; c.f = f;
  uint32_t r = c.u + 0x7fffu + ((c.u >> 16) & 1u);  // RNE
  return (u16)(r >> 16);
}
DEVFN void gload16(const void* g, void* lds_p) {
  __builtin_amdgcn_global_load_lds(
      (const __attribute__((address_space(1))) void*)g,
      (__attribute__((address_space(3))) void*)lds_p, 16, 0, 0);
}

// ---------------------------------------------------------------------------
// Convert fp32 X -> bf16 Xb
__global__ __launch_bounds__(256) void k_cvt_x(const float* __restrict__ x,
                                               u16* __restrict__ xb) {
  const size_t i = ((size_t)blockIdx.x * 256 + threadIdx.x) * 8;
  f32x4 a = *(const f32x4*)(x + i);
  f32x4 b = *(const f32x4*)(x + i + 4);
  u16x8 o;
#pragma unroll
  for (int j = 0; j < 4; ++j) { o[j] = f2bf(a[j]); o[4 + j] = f2bf(b[j]); }
  *(u16x8*)(xb + i) = o;
}

// ---------------------------------------------------------------------------
// Wt[g*1024+n][k] = W_g[k][n]  (bf16, B^T layout for the GEMM)
__global__ __launch_bounds__(256) void k_wt(const float* __restrict__ Wq,
                                            const float* __restrict__ Wk,
                                            const float* __restrict__ Wv,
                                            u16* __restrict__ Wt) {
  const int n = blockIdx.x * 256 + threadIdx.x;  // 0..1023
  const int kc = blockIdx.y;                     // k-chunk of 8
  const int g = blockIdx.z;                      // 0..2
  const float* W = (g == 0) ? Wq : (g == 1) ? Wk : Wv;
  u16x8 o;
#pragma unroll
  for (int j = 0; j < 8; ++j) o[j] = f2bf(W[(size_t)(kc * 8 + j) * 1024 + n]);
  *(u16x8*)(Wt + ((size_t)(g * 1024 + n)) * 1024 + kc * 8) = o;
}

// ---------------------------------------------------------------------------
// GEMM, R1-exact skeleton + conflict-free LDS reads + coalesced epilogue.
// 128x128 tile, BK=32, 4 waves (2Mx2N), 16KB single-buffer LDS, plain
// __syncthreads per K-tile (stage -> sync -> read+MFMA -> sync).
// Swizzle: col-slot XOR ((row>>1)&3) -> 2-way banks (free, m136); realized as
// pre-swizzled global source (linear gload_lds dest) + XOR on ds_read addr.
// Epilogue: C staged via LDS in two 64-row halves -> coalesced u16x8 stores;
// EPI=0 fuses bias + elu + per-(row,head) L2 norm for Q/K segments.
// EPI=0 (QKV): grid dim3(256,24), by: 0-7 Q, 8-15 K, 16-23 V.
// EPI=1 (ctx): grid dim3(256,8), Bt per-batch (Bt + batch*1M).
template <int EPI>
__global__ __launch_bounds__(256, 4) void k_g(
    const u16* __restrict__ A, const u16* __restrict__ Bt,
    u16* __restrict__ o0, u16* __restrict__ o1, u16* __restrict__ o2,
    const float* __restrict__ bias0, const float* __restrict__ bias1,
    const float* __restrict__ bias2) {
  __shared__ __align__(16) u16 lds[8192];  // A: 0..4095, B: 4096..8191 (u16)
  const int tid = threadIdx.x;
  const int w = tid >> 6, l = tid & 63;
  const int wm = w >> 1, wn = w & 1;
  const int bx = (int)blockIdx.x, by = (int)blockIdx.y;
  const long row0 = (long)bx * 128;
  const u16* Bt2 = Bt + (EPI == 1 ? ((size_t)(row0 >> 12) << 20) : (size_t)0);
  const long col0 = (long)by * 128;
  const int seg = (EPI == 0) ? (by >> 3) : 0;  // 0:Q 1:K 2:V
  const int colN = (EPI == 0) ? ((by & 7) * 128) : (int)col0;

  // staging: chunk c in 0..511 per matrix; row=c>>2, slot=c&3 (16B);
  // source col pre-swizzled: slot ^ ((row>>1)&3). Thread handles c0=tid
  // (rows 0..63) and c1=256+tid (rows 64..127; same swizzle bits).
  const int ksw = ((tid & 3) ^ ((tid >> 3) & 3)) << 3;  // u16 offset
  const u16* srcA = A + (row0 + (tid >> 2)) * 1024 + ksw;
  const u16* srcB = Bt2 + (col0 + (tid >> 2)) * 1024 + ksw;
  u16* dA0 = lds + w * 512;          // wave-uniform; lane writes +l*8 u16
  u16* dA1 = lds + 2048 + w * 512;
  u16* dB0 = lds + 4096 + w * 512;
  u16* dB1 = lds + 6144 + w * 512;

  // read bases (u16 idx): row*32 + ((l>>4)*8 ^ ((l>>1)&3)*8)
  const int rsw = (((l >> 4) ^ ((l >> 1) & 3)) << 3);
  const int aro = (wm * 64 + (l & 15)) * 32 + rsw;
  const int bro = 4096 + (wn * 64 + (l & 15)) * 32 + rsw;

  f32x4 acc[4][4];
#pragma unroll
  for (int i = 0; i < 4; ++i)
#pragma unroll
    for (int j = 0; j < 4; ++j) acc[i][j] = (f32x4){0.f, 0.f, 0.f, 0.f};

  for (int kt = 0; kt < 1024; kt += 32) {
    gload16(srcA + kt, dA0);
    gload16(srcA + 65536 + kt, dA1);   // row +64
    gload16(srcB + kt, dB0);
    gload16(srcB + 65536 + kt, dB1);
    __syncthreads();  // drains vmcnt -> tile visible
    bf16x8 af[4], bfg[4];
#pragma unroll
    for (int mf = 0; mf < 4; ++mf)
      af[mf] = *(const bf16x8*)(lds + aro + mf * 512);
#pragma unroll
    for (int nf = 0; nf < 4; ++nf)
      bfg[nf] = *(const bf16x8*)(lds + bro + nf * 512);
#pragma unroll
    for (int mf = 0; mf < 4; ++mf)
#pragma unroll
      for (int nf = 0; nf < 4; ++nf)
        acc[mf][nf] = __builtin_amdgcn_mfma_f32_16x16x32_bf16(
            af[mf], bfg[nf], acc[mf][nf], 0, 0, 0);
    __syncthreads();  // all reads done before next stage overwrites
  }

  // ---- Epilogue: two 64-row halves through 16KB LDS, coalesced stores.
  // u16 idx = rl*128 + ((cg ^ (rl&7))<<4) + (col&15), cg = col>>4.
  u16* cl = lds;
  const float* bias =
      (EPI == 0) ? ((seg == 0) ? bias0 : (seg == 1) ? bias1 : bias2) : nullptr;
  u16* outp = (EPI == 0) ? ((seg == 0) ? o0 : (seg == 1) ? o1 : o2) : o0;
#pragma unroll
  for (int h = 0; h < 2; ++h) {
    if (wm == h) {
#pragma unroll
      for (int nf = 0; nf < 4; ++nf) {
        const int col = wn * 64 + (l & 15) + nf * 16;
        const float bv_ = (EPI == 0) ? bias[colN + col] : 0.f;
#pragma unroll
        for (int mf = 0; mf < 4; ++mf)
#pragma unroll
          for (int r = 0; r < 4; ++r) {
            const int rl = mf * 16 + ((l >> 4) << 2) + r;  // 0..63
            float v = acc[mf][nf][r];
            if (EPI == 0) {
              v += bv_;
              if (seg < 2) v = v > 0.f ? v : expm1f(v);  // elu
            }
            cl[rl * 128 + (((col >> 4) ^ (rl & 7)) << 4) + (col & 15)] =
                f2bf(v);
          }
      }
    }
    __syncthreads();
    const int s = tid & 15;  // 16B col-slot
#pragma unroll
    for (int i = 0; i < 4; ++i) {
      const int rl = i * 16 + (tid >> 4);
      u16x8 val = *(const u16x8*)((const char*)cl + rl * 256 +
                                  (((s >> 1) ^ (rl & 7)) << 5) +
                                  ((s & 1) << 4));
      if (EPI == 0 && seg < 2) {  // fused L2 norm: 8 slots cover one head
        float f[8], ss = 0.f;
#pragma unroll
        for (int j = 0; j < 8; ++j) { f[j] = bf2f(val[j]); ss += f[j] * f[j]; }
        ss += __shfl_xor(ss, 1);
        ss += __shfl_xor(ss, 2);
        ss += __shfl_xor(ss, 4);
        const float rn = rsqrtf(ss);
#pragma unroll
        for (int j = 0; j < 8; ++j) val[j] = f2bf(f[j] * rn);
      }
      *(u16x8*)(outp + (size_t)(row0 + h * 64 + rl) * 1024 + colN + s * 8) =
          val;
    }
    __syncthreads();
  }
}

// ---------------------------------------------------------------------------
// kv partials via MFMA: kvp[sc][b][h][d][e] = sum_{s in quarter} kn[s,d]*v[s,e]
__global__ __launch_bounds__(256) void k_kv(const u16* __restrict__ kn,
                                            const u16* __restrict__ vv,
                                            float* __restrict__ kvp) {
  __shared__ __align__(16) char lds[69632];  // 4 regions x 17408 B
  const int tid = threadIdx.x, w = tid >> 6, l = tid & 63;
  const int bid = blockIdx.x;  // sc + 4*(h + 16*b)
  const int sc = bid & 3, h = (bid >> 2) & 15, b = bid >> 6;
  const int tp = l >> 3, dgrp = l & 7;
  char* myk = lds + w * 17408;       // knT tile [64 d][64 s] u16 (128B rows)
  char* myv = myk + 8192;            // vT tile
  const long Tw = (long)b * 4096 + sc * 1024 + w * 256;
  const int d0 = dgrp * 8;

  f32x4 acc[4][4];
#pragma unroll
  for (int i = 0; i < 4; ++i)
#pragma unroll
    for (int j = 0; j < 4; ++j) acc[i][j] = (f32x4){0.f, 0.f, 0.f, 0.f};

  for (int st = 0; st < 4; ++st) {
    // ---- transpose-stage 64 tokens x 64 d for kn and v
#pragma unroll
    for (int ro = 0; ro < 4; ++ro) {
      const int tl = ro * 16 + tp * 2;  // even local token
      const long T = Tw + st * 64 + tl;
      const u16* kp = kn + (size_t)T * 1024 + h * 64 + d0;
      const u16* vp = vv + (size_t)T * 1024 + h * 64 + d0;
      u16x8 k0 = *(const u16x8*)kp, k1 = *(const u16x8*)(kp + 1024);
      u16x8 v0 = *(const u16x8*)vp, v1 = *(const u16x8*)(vp + 1024);
#pragma unroll
      for (int j = 0; j < 8; ++j) {
        const int d = d0 + j;
        const int sw = (d & 8) ? 32 : 0;
        *(uint32_t*)(myk + d * 128 + ((tl * 2) ^ sw)) =
            (uint32_t)k0[j] | ((uint32_t)k1[j] << 16);
        *(uint32_t*)(myv + d * 128 + ((tl * 2) ^ sw)) =
            (uint32_t)v0[j] | ((uint32_t)v1[j] << 16);
      }
    }
    // ---- compute: D[d][e] += knT-tile . vT-tile  (K = 64 = 2 slices)
#pragma unroll
    for (int ksl = 0; ksl < 2; ++ksl) {
      const int sb = (ksl * 64 + (l >> 4) * 16) ^ ((l & 8) ? 32 : 0);
      bf16x8 a[4], bb[4];
#pragma unroll
      for (int mf = 0; mf < 4; ++mf)
        a[mf] = *(const bf16x8*)(myk + (mf * 16 + (l & 15)) * 128 + sb);
#pragma unroll
      for (int nf = 0; nf < 4; ++nf)
        bb[nf] = *(const bf16x8*)(myv + (nf * 16 + (l & 15)) * 128 + sb);
#pragma unroll
      for (int mf = 0; mf < 4; ++mf)
#pragma unroll
        for (int nf = 0; nf < 4; ++nf)
          acc[mf][nf] = __builtin_amdgcn_mfma_f32_16x16x32_bf16(
              a[mf], bb[nf], acc[mf][nf], 0, 0, 0);
    }
  }

  // ---- block reduction of 4 wave partials (rows padded to 68 f32)
  __syncthreads();
  float* lf = (float*)(lds + w * 17408);
#pragma unroll
  for (int mf = 0; mf < 4; ++mf)
#pragma unroll
    for (int nf = 0; nf < 4; ++nf)
#pragma unroll
      for (int r = 0; r < 4; ++r)
        lf[(mf * 16 + (l >> 4) * 4 + r) * 68 + nf * 16 + (l & 15)] =
            acc[mf][nf][r];
  __syncthreads();
  float* op = kvp + ((size_t)(sc * 8 + b) * 16 + h) * 4096;
  const float* l0 = (const float*)lds;
  const int dd = tid >> 2, eb = (tid & 3) * 16;
#pragma unroll
  for (int c = 0; c < 4; ++c) {
    f32x4 s = *(const f32x4*)(l0 + dd * 68 + eb + c * 4);
#pragma unroll
    for (int w2 = 1; w2 < 4; ++w2)
      s += *(const f32x4*)(l0 + w2 * 4352 + dd * 68 + eb + c * 4);
    *(f32x4*)(op + tid * 16 + c * 4) = s;
  }
}

// ---------------------------------------------------------------------------
// M2t[b][n][h*64+d] = (1/8) * sum_e kv[b,h][d][e] * Wd[h*64+e][n]   (bf16)
__global__ __launch_bounds__(256) void k_m2(const float* __restrict__ kvp,
                                            const float* __restrict__ Wd,
                                            u16* __restrict__ M2t) {
  const int tid = threadIdx.x;
  const int nb = blockIdx.x, h = blockIdx.y, b = blockIdx.z;
  const int d = tid >> 2, eg = tid & 3;
  const size_t kbase = (((size_t)(b * 16 + h)) * 64 + d) * 64 + eg * 16;
  float kvr[16];
#pragma unroll
  for (int c = 0; c < 4; ++c) {
    f32x4 s = *(const f32x4*)(kvp + kbase + c * 4);
#pragma unroll
    for (int sc = 1; sc < 4; ++sc)
      s += *(const f32x4*)(kvp + (size_t)sc * 524288 + kbase + c * 4);
#pragma unroll
    for (int j = 0; j < 4; ++j) kvr[c * 4 + j] = s[j];
  }
  const float* wcol = Wd + ((size_t)h * 64 + eg * 16) * 1024;
  for (int n = nb * 256; n < nb * 256 + 256; ++n) {
    float p = 0.f;
#pragma unroll
    for (int i = 0; i < 16; ++i) p += kvr[i] * wcol[(size_t)i * 1024 + n];
    p += __shfl_xor(p, 1);
    p += __shfl_xor(p, 2);
    if (eg == 0)
      M2t[((size_t)b * 1024 + n) * 1024 + h * 64 + d] = f2bf(p * 0.125f);
  }
}

// ---------------------------------------------------------------------------
// LayerNorm(hid + bd + xb) * gamma + beta  -> fp32 out
__global__ __launch_bounds__(256) void k_ln(const u16* __restrict__ hid,
                                            const u16* __restrict__ xb,
                                            const float* __restrict__ bd,
                                            const float* __restrict__ g,
                                            const float* __restrict__ be,
                                            float* __restrict__ out) {
  const int tid = threadIdx.x, w = tid >> 6, l = tid & 63;
  const size_t base = (size_t)blockIdx.x * 1024 + tid * 4;
  u16x4 h4 = *(const u16x4*)(hid + base);
  u16x4 x4 = *(const u16x4*)(xb + base);
  f32x4 bd4 = *(const f32x4*)(bd + tid * 4);
  float v[4];
#pragma unroll
  for (int j = 0; j < 4; ++j) v[j] = bf2f(h4[j]) + bf2f(x4[j]) + bd4[j];
  float s = v[0] + v[1] + v[2] + v[3];
  float ss = v[0] * v[0] + v[1] * v[1] + v[2] * v[2] + v[3] * v[3];
#pragma unroll
  for (int o = 32; o > 0; o >>= 1) {
    s += __shfl_xor(s, o);
    ss += __shfl_xor(ss, o);
  }
  __shared__ float red[8];
  if (l == 0) { red[w] = s; red[w + 4] = ss; }
  __syncthreads();
  s = red[0] + red[1] + red[2] + red[3];
  ss = red[4] + red[5] + red[6] + red[7];
  const float mu = s * (1.0f / 1024.0f);
  const float var = ss * (1.0f / 1024.0f) - mu * mu;
  const float rstd = rsqrtf(var + 1e-12f);
  f32x4 g4 = *(const f32x4*)(g + tid * 4);
  f32x4 b4 = *(const f32x4*)(be + tid * 4);
  f32x4 o;
#pragma unroll
  for (int j = 0; j < 4; ++j) o[j] = (v[j] - mu) * rstd * g4[j] + b4[j];
  *(f32x4*)(out + base) = o;
}

// ---------------------------------------------------------------------------
extern "C" void kernel_launch(void* const* d_in, const int* in_sizes, int n_in,
                              void* d_out, int out_size, void* d_ws,
                              size_t ws_size, hipStream_t stream) {
  const float* X = (const float*)d_in[0];
  const float* Wq = (const float*)d_in[1];
  const float* bq = (const float*)d_in[2];
  const float* Wk = (const float*)d_in[3];
  const float* bk = (const float*)d_in[4];
  const float* Wv = (const float*)d_in[5];
  const float* bv = (const float*)d_in[6];
  const float* Wd = (const float*)d_in[7];
  const float* bd = (const float*)d_in[8];
  const float* gamma = (const float*)d_in[9];
  const float* beta = (const float*)d_in[10];
  float* out = (float*)d_out;

  char* ws = (char*)d_ws;
  u16* Xb = (u16*)(ws);                       // 64 MiB
  u16* Wt = (u16*)(ws + 67108864);            // 6 MiB  [3072][1024] bf16
  u16* eq = (u16*)(ws + 73400320);            // 64 MiB (qn, normalized in epi)
  u16* ek = (u16*)(ws + 140509184);           // 64 MiB (kn; reused as hid)
  u16* vb = (u16*)(ws + 207618048);           // 64 MiB
  float* kvp = (float*)(ws + 276824064);      // 8 MiB (4 partials)
  u16* M2t = (u16*)(ws + 285212672);          // 16 MiB  [8][1024][1024] bf16
  // total ws use: 301,989,888 bytes

  k_cvt_x<<<16384, 256, 0, stream>>>(X, Xb);
  k_wt<<<dim3(4, 128, 3), 256, 0, stream>>>(Wq, Wk, Wv, Wt);
  k_g<0><<<dim3(256, 24), 256, 0, stream>>>(Xb, Wt, eq, ek, vb, bq, bk, bv);
  k_kv<<<512, 256, 0, stream>>>(ek, vb, kvp);
  k_m2<<<dim3(4, 16, 8), 256, 0, stream>>>(kvp, Wd, M2t);
  k_g<1><<<dim3(256, 8), 256, 0, stream>>>(eq, M2t, ek, nullptr, nullptr,
                                           nullptr, nullptr, nullptr);
  k_ln<<<32768, 256, 0, stream>>>(ek, Xb, bd, gamma, beta, out);
}